// Round 9
// baseline (115.731 us; speedup 1.0000x reference)
//
#include <hip/hip_runtime.h>

// Segmented CRF forward (OneCrfCCKSDecoder), exp-domain + MFMA, R16.
// T=128, B=512, E=128, EVENTLEN=8, NEG=-10000.
//
// R15 post-mortem: the 268MB/43us workspace fill is UNCONDITIONAL harness
// baggage (persists with zero d_ws usage) -- ~43us of every iteration,
// baseline included. Controllable budget: prep ~10 + crf <43 + overhead.
//
// R16 theory: crf's ~340ns/step (vs ~130ns chain latency) is SIMD-sharing
// stretch -- 8 waves on 4 SIMDs means each engine wave's latency-bound
// serial chain round-robins issue with a co-resident wave. Evidence: R14
// went 8->16 waves/block and crf doubled (43 -> 80-88). So go 8->4 waves
// (1 wave/SIMD): wave w owns j-tiles {2w, 2w+1} (2 publishes, 8 MFMAs as
// 4 independent 2-chains; B-frags shared across both tiles so LDS reads
// stay 4/lane). Barrier syncs 4 waves at 1/SIMD. All layouts/swizzles/
// renorm bookkeeping identical to validated R13/R15, re-indexed w -> jt.
//
// MFMA layouts (validated): A[m=lane&15][k=32kap+8q+i],
// B[k=32kap+8q+i][n=lane&15], D[m=4q+r][n=lane&15].

typedef _Float16 f16x4 __attribute__((ext_vector_type(4)));
typedef _Float16 f16x8 __attribute__((ext_vector_type(8)));
typedef float    f32x4 __attribute__((ext_vector_type(4)));

#define NEG_VAL   (-10000.0f)
#define C_SCALE   0.0024787521766663585f   // e^-6
#define LOG_C     6.0f

// order own LDS writes + join workgroup; does NOT drain vmcnt (feat
// prefetch loads stay in flight across the barrier)
#define LDS_BARRIER() asm volatile("s_waitcnt lgkmcnt(0)\n\ts_barrier" ::: "memory")

// module-scope ef buffer: 128*512*128 f16 = 16.78 MB, allocated at load.
__device__ __align__(16) _Float16 g_ef[128 * 512 * 128];

// ---- pre-pass: ef16 in engine layout ----
// g_ef[t*65536 + g*2048 + jt*256 + bloc*16 + q*4 + r]
//   = f16( exp(feats[t][16g+bloc][16jt+4q+r]) * C_SCALE )
__global__ __launch_bounds__(256)
void prep_exp(const float* __restrict__ feats)
{
    int id = blockIdx.x * 256 + threadIdx.x;           // 524288 threads
    #pragma unroll
    for (int it = 0; it < 4; ++it, id += 524288) {     // 4x grid-stride = 2.1M
        const int jj = id & 31;                        // j-quad index, j=4*jj
        const int tb = id >> 5;                        // t*512 + b
        const int b  = tb & 511;
        const int t  = tb >> 9;
        f32x4 x = *(const f32x4*)(feats + (size_t)tb * 128 + 4 * jj);
        auto lo = __builtin_amdgcn_cvt_pkrtz(__expf(x[0]) * C_SCALE,
                                             __expf(x[1]) * C_SCALE);
        auto hi = __builtin_amdgcn_cvt_pkrtz(__expf(x[2]) * C_SCALE,
                                             __expf(x[3]) * C_SCALE);
        f16x4 o;
        o[0] = (_Float16)lo[0]; o[1] = (_Float16)lo[1];
        o[2] = (_Float16)hi[0]; o[3] = (_Float16)hi[1];
        const int off = t * 65536 + (b >> 4) * 2048 + (jj >> 2) * 256
                      + (b & 15) * 16 + (jj & 3) * 4;
        *(f16x4*)(g_ef + off) = o;
    }
}

__device__ inline f16x4 cvt4(f32x4 a) {
    auto lo = __builtin_amdgcn_cvt_pkrtz(a[0], a[1]);
    auto hi = __builtin_amdgcn_cvt_pkrtz(a[2], a[3]);
    f16x4 o;
    o[0] = (_Float16)lo[0]; o[1] = (_Float16)lo[1];
    o[2] = (_Float16)hi[0]; o[3] = (_Float16)hi[1];
    return o;
}

__global__ __launch_bounds__(256, 1)
void crf_fwd(const float* __restrict__ trans,   // [128][128] f32
             float* __restrict__ out)
{
    const int tid  = threadIdx.x;
    const int w    = tid >> 6;         // wave id 0..3, owns j-tiles {2w, 2w+1}
    const int lane = tid & 63;
    const int bloc = lane & 15;        // batch-in-tile (n role; m role for A)
    const int q    = lane >> 4;        // quad 0..3
    const int b    = blockIdx.x * 16 + bloc;   // global batch

    // ---- A fragments: exp(T) rows j = 16jt + bloc, k = 32kap + 8q + i ----
    f16x8 Afrag[2][4];
    f32x4 te[2];
    #pragma unroll
    for (int jj = 0; jj < 2; ++jj) {
        const int jt = 2 * w + jj;
        const float* rowp = trans + (size_t)(16 * jt + bloc) * 128;
        #pragma unroll
        for (int kap = 0; kap < 4; ++kap) {
            const f32x4* p = (const f32x4*)(rowp + 32 * kap + 8 * q);
            f32x4 x = p[0], y = p[1];
            f16x8 f;
            f[0] = (_Float16)__expf(x[0]); f[1] = (_Float16)__expf(x[1]);
            f[2] = (_Float16)__expf(x[2]); f[3] = (_Float16)__expf(x[3]);
            f[4] = (_Float16)__expf(y[0]); f[5] = (_Float16)__expf(y[1]);
            f[6] = (_Float16)__expf(y[2]); f[7] = (_Float16)__expf(y[3]);
            Afrag[jj][kap] = f;
        }
        // te in D layout: te[jj][r] = exp(trans[127][16jt + 4q + r])
        f32x4 x = *(const f32x4*)(trans + 127 * 128 + 16 * jt + 4 * q);
        te[jj][0] = __expf(x[0]); te[jj][1] = __expf(x[1]);
        te[jj][2] = __expf(x[2]); te[jj][3] = __expf(x[3]);
    }

    // ---- LDS: H double-buffered (2 x 16 batches x 128 k f16, 16B chunks
    //           XOR-swizzled by bloc), Spart/Mpart for boundary exchange ----
    __shared__ __align__(16) char  Hbuf[8192];
    __shared__ float Spart[16 * 4];
    __shared__ float Mpart[16 * 4];

    int waddr[2], raddr[4];
    #pragma unroll
    for (int jj = 0; jj < 2; ++jj) {
        const int jt = 2 * w + jj;
        waddr[jj] = bloc * 256 + (((2 * jt + (q >> 1)) ^ bloc) * 16) + 8 * (q & 1);
    }
    #pragma unroll
    for (int kap = 0; kap < 4; ++kap)
        raddr[kap] = bloc * 256 + (((4 * kap + q) ^ bloc) * 16);

    // ---- feat pipeline: 2x 8B f16x4 loads per step (one per j-tile) ----
    const _Float16* efb0 = g_ef + blockIdx.x * 2048 + (2 * w)     * 256 + bloc * 16 + q * 4;
    const _Float16* efb1 = g_ef + blockIdx.x * 2048 + (2 * w + 1) * 256 + bloc * 16 + q * 4;
    f16x4 cur[2], nx1[2], nx2[2];      // ef16 for t, t+1, t+2
    cur[0] = *(const f16x4*)(efb0 + 1 * 65536);
    cur[1] = *(const f16x4*)(efb1 + 1 * 65536);
    nx1[0] = *(const f16x4*)(efb0 + 2 * 65536);
    nx1[1] = *(const f16x4*)(efb1 + 2 * 65536);
    nx2[0] = *(const f16x4*)(efb0 + 3 * 65536);
    nx2[1] = *(const f16x4*)(efb1 + 3 * 65536);

    f32x4 acc[2];                      // u[b][j], j = 16(2w+jj) + 4q + r
    acc[0] = (f32x4){1.f, 1.f, 1.f, 1.f};
    acc[1] = (f32x4){1.f, 1.f, 1.f, 1.f};
    float M     = (b == 0) ? 0.0f : NEG_VAL;  // init_fv zeroes only batch-0 row
    float alpha = 0.0f;
    int hb = 0;                        // H double-buffer offset

    #pragma unroll 8
    for (int t = 1; t < 128; ++t) {
        const bool upd = (t & 7) != 0;

        if (upd) {
            // ---- publish h = f16(acc) * ef16 (scale inside ef; M += 6) ----
            M += LOG_C;
            f16x4 hh0 = cvt4(acc[0]) * cur[0];
            f16x4 hh1 = cvt4(acc[1]) * cur[1];
            *(f16x4*)(Hbuf + hb + waddr[0]) = hh0;
            *(f16x4*)(Hbuf + hb + waddr[1]) = hh1;
            LDS_BARRIER();

            f16x8 B0 = *(const f16x8*)(Hbuf + hb + raddr[0]);
            f16x8 B1 = *(const f16x8*)(Hbuf + hb + raddr[1]);
            f16x8 B2 = *(const f16x8*)(Hbuf + hb + raddr[2]);
            f16x8 B3 = *(const f16x8*)(Hbuf + hb + raddr[3]);

            // ---- 8 MFMAs: 2 j-tiles x 4, four independent 2-chains ----
            f32x4 z = {0.f, 0.f, 0.f, 0.f};
            f32x4 da0 = __builtin_amdgcn_mfma_f32_16x16x32_f16(Afrag[0][0], B0, z, 0, 0, 0);
            f32x4 db0 = __builtin_amdgcn_mfma_f32_16x16x32_f16(Afrag[0][1], B1, z, 0, 0, 0);
            f32x4 da1 = __builtin_amdgcn_mfma_f32_16x16x32_f16(Afrag[1][0], B0, z, 0, 0, 0);
            f32x4 db1 = __builtin_amdgcn_mfma_f32_16x16x32_f16(Afrag[1][1], B1, z, 0, 0, 0);
            da0 = __builtin_amdgcn_mfma_f32_16x16x32_f16(Afrag[0][2], B2, da0, 0, 0, 0);
            db0 = __builtin_amdgcn_mfma_f32_16x16x32_f16(Afrag[0][3], B3, db0, 0, 0, 0);
            da1 = __builtin_amdgcn_mfma_f32_16x16x32_f16(Afrag[1][2], B2, da1, 0, 0, 0);
            db1 = __builtin_amdgcn_mfma_f32_16x16x32_f16(Afrag[1][3], B3, db1, 0, 0, 0);
            acc[0] = da0 + db0;
            acc[1] = da1 + db1;
            hb ^= 4096;                // alternate H buffer
        } else {
            // ---- boundary: per-wave partials (sum for alpha, max for renorm)
            float s = acc[0][0] * te[0][0] + acc[0][1] * te[0][1]
                    + acc[0][2] * te[0][2] + acc[0][3] * te[0][3]
                    + acc[1][0] * te[1][0] + acc[1][1] * te[1][1]
                    + acc[1][2] * te[1][2] + acc[1][3] * te[1][3];
            float m = fmaxf(fmaxf(fmaxf(acc[0][0], acc[0][1]),
                                  fmaxf(acc[0][2], acc[0][3])),
                            fmaxf(fmaxf(acc[1][0], acc[1][1]),
                                  fmaxf(acc[1][2], acc[1][3])));
            s += __shfl_xor(s, 16, 64);
            s += __shfl_xor(s, 32, 64);
            m = fmaxf(m, __shfl_xor(m, 16, 64));
            m = fmaxf(m, __shfl_xor(m, 32, 64));
            if (q == 0) {
                Spart[bloc * 4 + w] = s;
                Mpart[bloc * 4 + w] = m;
            }
            LDS_BARRIER();

            f32x4 sa = *(const f32x4*)&Spart[bloc * 4];
            f32x4 ma = *(const f32x4*)&Mpart[bloc * 4];
            float r    = (sa[0] + sa[1]) + (sa[2] + sa[3]);
            float cmax = fmaxf(fmaxf(ma[0], ma[1]), fmaxf(ma[2], ma[3]));

            alpha += M + __logf(r);    // per-batch, replicated over q & waves
            // exact renorm: scale acc permanently, book into M
            const float inv = __builtin_amdgcn_rcpf(cmax);
            acc[0][0] *= inv; acc[0][1] *= inv; acc[0][2] *= inv; acc[0][3] *= inv;
            acc[1][0] *= inv; acc[1][1] *= inv; acc[1][2] *= inv; acc[1][3] *= inv;
            M += __logf(cmax);
        }

        // ---- rotate feat pipeline (2x 8B prefetch, 3 steps ahead) ----
        if (t + 1 < 128) {
            cur[0] = nx1[0]; cur[1] = nx1[1];
            nx1[0] = nx2[0]; nx1[1] = nx2[1];
            if (t + 3 < 128) {
                nx2[0] = *(const f16x4*)(efb0 + (size_t)(t + 3) * 65536);
                nx2[1] = *(const f16x4*)(efb1 + (size_t)(t + 3) * 65536);
            }
        }
    }

    // ---- terminal accumulation (sum exchange only) ----
    {
        float s = acc[0][0] * te[0][0] + acc[0][1] * te[0][1]
                + acc[0][2] * te[0][2] + acc[0][3] * te[0][3]
                + acc[1][0] * te[1][0] + acc[1][1] * te[1][1]
                + acc[1][2] * te[1][2] + acc[1][3] * te[1][3];
        s += __shfl_xor(s, 16, 64);
        s += __shfl_xor(s, 32, 64);
        if (q == 0) Spart[bloc * 4 + w] = s;
        LDS_BARRIER();
        f32x4 sa = *(const f32x4*)&Spart[bloc * 4];
        float r = (sa[0] + sa[1]) + (sa[2] + sa[3]);
        alpha += M + __logf(r);
    }

    // alpha is replicated across q and waves; reduce in wave 0.
    if (w == 0) {
        float v = alpha;               // 64 lanes = 4x replication of 16 batches
        #pragma unroll
        for (int off = 1; off < 64; off <<= 1)
            v += __shfl_xor(v, off, 64);
        if (lane == 0)
            atomicAdd(out, v * (1.0f / (4.0f * 512.0f * 16.0f)));
    }
}

extern "C" void kernel_launch(void* const* d_in, const int* in_sizes, int n_in,
                              void* d_out, int out_size, void* d_ws, size_t ws_size,
                              hipStream_t stream) {
    const float* feats = (const float*)d_in[0];   // [128,512,128] f32
    const float* trans = (const float*)d_in[1];   // [128,128] f32
    float* out = (float*)d_out;                   // scalar f32

    (void)hipMemsetAsync(out, 0, sizeof(float), stream);
    prep_exp<<<2048, 256, 0, stream>>>(feats);
    crf_fwd<<<32, 256, 0, stream>>>(trans, out);
}